// Round 14
// baseline (367.953 us; speedup 1.0000x reference)
//
#include <hip/hip_runtime.h>
#include <math.h>

#define N_TOT 524288
#define B_GR  16384
#define CAPR  64

#define LOG2E 1.44269504088896f
#define LN2   0.69314718055995f

typedef __attribute__((ext_vector_type(8))) short bf16x8;
typedef __attribute__((ext_vector_type(4))) float f32x4;

// ---------------- small device helpers ----------------
__device__ __forceinline__ float fexp2(float x) { return __builtin_amdgcn_exp2f(x); }
__device__ __forceinline__ float flog2(float x) { return __builtin_amdgcn_logf(x); }
__device__ __forceinline__ float frcp(float x)  { return __builtin_amdgcn_rcpf(x); }
__device__ __forceinline__ float sigf(float x)  { return frcp(1.0f + fexp2(-x * LOG2E)); }

// bf16 pack/unpack (RNE)
__device__ __forceinline__ unsigned int f2bf(float x) {
  unsigned int u = __float_as_uint(x);
  return (u + 0x7FFFu + ((u >> 16) & 1u)) >> 16;
}
__device__ __forceinline__ float bf2f(unsigned int s) {
  return __uint_as_float(s << 16);
}

// ---- DPP-based 64-lane sum (KL path, fallback path) ----
template <int CTRL>
__device__ __forceinline__ float dppadd(float v) {
  return v + __int_as_float(__builtin_amdgcn_update_dpp(
      0, __float_as_int(v), CTRL, 0xF, 0xF, true));
}
__device__ __forceinline__ float wave_red(float v) {
  v = dppadd<0x111>(v);   // row_shr:1
  v = dppadd<0x112>(v);   // row_shr:2
  v = dppadd<0x114>(v);   // row_shr:4
  v = dppadd<0x118>(v);   // row_shr:8
  v = dppadd<0x142>(v);   // row_bcast15
  v = dppadd<0x143>(v);   // row_bcast31
  return __int_as_float(__builtin_amdgcn_readlane(__float_as_int(v), 63));
}

// ---- butterfly multi-reduce merge: combines two node-vectors over lane-offset off.
// Result lane l: (l&off)==0 -> partial of a over {l, l^off}; else partial of b.
__device__ __forceinline__ float mergeRed(float a, float b, int off, int lane) {
  float as = __shfl_xor(a, off);
  float bs = __shfl_xor(b, off);
  return (lane & off) ? (b + bs) : (a + as);
}

// ---- batched attention: all 64 node dots at once (e_n lands at lane n),
// vectorized softmax (ONE exp2), readlane-broadcast weighted sum.
__device__ __forceinline__ float attn_batched(const unsigned int (&pk)[CAPR / 2], int cnt,
                                              float qv2, int lane) {
  float m2[16];
#pragma unroll
  for (int k = 0; k < 16; k++) {
    unsigned int pa = pk[2 * k], pb = pk[2 * k + 1];
    float a0 = bf2f(pa & 0xffffu) * qv2;
    float a1 = bf2f(pa >> 16) * qv2;
    float b0 = bf2f(pb & 0xffffu) * qv2;
    float b1 = bf2f(pb >> 16) * qv2;
    float u = mergeRed(a0, a1, 1, lane);
    float v = mergeRed(b0, b1, 1, lane);
    m2[k] = mergeRed(u, v, 2, lane);
  }
#pragma unroll
  for (int k = 0; k < 8; k++) m2[k] = mergeRed(m2[2 * k], m2[2 * k + 1], 4, lane);
#pragma unroll
  for (int k = 0; k < 4; k++) m2[k] = mergeRed(m2[2 * k], m2[2 * k + 1], 8, lane);
#pragma unroll
  for (int k = 0; k < 2; k++) m2[k] = mergeRed(m2[2 * k], m2[2 * k + 1], 16, lane);
  float e = mergeRed(m2[0], m2[1], 32, lane);   // lane n holds e_n
  e = (lane < cnt) ? e : -3.0e38f;
  float M = e;
#pragma unroll
  for (int off = 32; off > 0; off >>= 1) M = fmaxf(M, __shfl_xor(M, off));
  float w = fexp2(e - M);                        // one exp2 for ALL nodes
  float denom = w;
#pragma unroll
  for (int off = 32; off > 0; off >>= 1) denom += __shfl_xor(denom, off);
  float racc = 0.f;
#pragma unroll
  for (int np = 0; np < CAPR / 2; np++) {
    unsigned int p2 = pk[np];
    float wA = __shfl(w, 2 * np);
    float wB = __shfl(w, 2 * np + 1);
    racc = fmaf(wA, bf2f(p2 & 0xffffu), racc);
    racc = fmaf(wB, bf2f(p2 >> 16), racc);
  }
  return racc / denom;
}

// ---------------- 64x64 f32 register-tiled GEMM pieces (k_linear) ----------------
__device__ __forceinline__ void load_A64(const float* __restrict__ A, size_t lda, int n0, int k0,
                                         float (*As)[68], int tid) {
#pragma unroll
  for (int s = 0; s < 4; s++) {
    int e4 = tid * 4 + s * 1024;
    int r = e4 >> 6, k = e4 & 63;
    *(float4*)&As[r][k] = *(const float4*)&A[(size_t)(n0 + r) * lda + k0 + k];
  }
}
__device__ __forceinline__ void mm64(const float (*As)[68], const float (*Wt)[68],
                                     int ty, int tx, float acc[4][4]) {
#pragma unroll
  for (int k4 = 0; k4 < 64; k4 += 4) {
    float4 b0 = *(const float4*)&Wt[k4 + 0][tx * 4];
    float4 b1 = *(const float4*)&Wt[k4 + 1][tx * 4];
    float4 b2 = *(const float4*)&Wt[k4 + 2][tx * 4];
    float4 b3 = *(const float4*)&Wt[k4 + 3][tx * 4];
#pragma unroll
    for (int i = 0; i < 4; i++) {
      float4 a = *(const float4*)&As[ty * 4 + i][k4];
      acc[i][0] = fmaf(a.w, b3.x, fmaf(a.z, b2.x, fmaf(a.y, b1.x, fmaf(a.x, b0.x, acc[i][0]))));
      acc[i][1] = fmaf(a.w, b3.y, fmaf(a.z, b2.y, fmaf(a.y, b1.y, fmaf(a.x, b0.y, acc[i][1]))));
      acc[i][2] = fmaf(a.w, b3.z, fmaf(a.z, b2.z, fmaf(a.y, b1.z, fmaf(a.x, b0.z, acc[i][2]))));
      acc[i][3] = fmaf(a.w, b3.w, fmaf(a.z, b2.w, fmaf(a.y, b1.w, fmaf(a.x, b0.w, acc[i][3]))));
    }
  }
}

// ---------------- K0a: graph offsets ----------------
__global__ void k_offsets(const int* __restrict__ idx, int* __restrict__ off) {
  int b = blockIdx.x * blockDim.x + threadIdx.x;
  if (b > B_GR) return;
  if (b == B_GR) { off[B_GR] = N_TOT; return; }
  int lo = 0, hi = N_TOT;
  while (lo < hi) { int mid = (lo + hi) >> 1; if (idx[mid] < b) lo = mid + 1; else hi = mid; }
  off[b] = lo;
}

// ---------------- K0b: pre-transpose weights; RTg; bf16 B-fragments ----------------
__global__ void k_prep(const float* __restrict__ w1, const float* __restrict__ pw1,
                       const float* __restrict__ pw2, const float* __restrict__ pw3,
                       const float* __restrict__ wih,
                       float* __restrict__ pw1T, float* __restrict__ pw2T,
                       float* __restrict__ pw3T, float* __restrict__ rtg,
                       unsigned short* __restrict__ wfragb) {
  int t = blockIdx.x * 256 + threadIdx.x;
  for (int i = t; i < 256 * 128; i += 16384){ int r = i >> 7, c = i & 127; pw1T[c * 256 + r] = pw1[i]; }
  for (int i = t; i < 128 * 256; i += 16384){ int r = i >> 8, c = i & 255; pw2T[c * 128 + r] = pw2[i]; }
  for (int i = t; i < 64 * 128; i += 16384) { int r = i >> 7, c = i & 127; pw3T[c * 64 + r]  = pw3[i]; }
  for (int i = t; i < 64 * 64 * 4; i += 16384) {
    int k = i >> 8, rem = i & 255, d = rem >> 2, j = rem & 3;
    rtg[i] = wih[(size_t)(j * 64 + d) * 128 + 64 + k];
  }
  for (int i = t; i < 8 * 64 * 8; i += 16384) {
    int f = i >> 9, lane = (i >> 3) & 63, j = i & 7;
    int ct = f >> 1, kh = f & 1;
    int k = kh * 32 + (lane >> 4) * 8 + j;
    int col = ct * 16 + (lane & 15);
    wfragb[i] = (unsigned short)f2bf(w1[(size_t)col * 64 + k]);
  }
}

// ---------------- K1: MFMA h = X@W1^T + b1 -> bf16 h; stats partials ----------------
__global__ __launch_bounds__(256) void k_bn_stats(const float* __restrict__ X,
                                                  const unsigned short* __restrict__ wfragb,
                                                  const float* __restrict__ b1, unsigned short* __restrict__ h,
                                                  float* __restrict__ pSum, float* __restrict__ pSq) {
  __shared__ float redS[16][64];
  __shared__ float redQ[16][64];
  int tid = threadIdx.x, w = tid >> 6, l = tid & 63;
  int n0 = blockIdx.x * 64;
  int r0 = w * 16;
  int arow = n0 + r0 + (l & 15);
  int kb = (l >> 4) * 8;
  const float* xr = X + (size_t)arow * 64 + kb;
  float4 a00 = *(const float4*)&xr[0];
  float4 a01 = *(const float4*)&xr[4];
  float4 a10 = *(const float4*)&xr[32];
  float4 a11 = *(const float4*)&xr[36];
  bf16x8 A0, A1;
  A0[0] = (short)f2bf(a00.x); A0[1] = (short)f2bf(a00.y); A0[2] = (short)f2bf(a00.z); A0[3] = (short)f2bf(a00.w);
  A0[4] = (short)f2bf(a01.x); A0[5] = (short)f2bf(a01.y); A0[6] = (short)f2bf(a01.z); A0[7] = (short)f2bf(a01.w);
  A1[0] = (short)f2bf(a10.x); A1[1] = (short)f2bf(a10.y); A1[2] = (short)f2bf(a10.z); A1[3] = (short)f2bf(a10.w);
  A1[4] = (short)f2bf(a11.x); A1[5] = (short)f2bf(a11.y); A1[6] = (short)f2bf(a11.z); A1[7] = (short)f2bf(a11.w);
  const bf16x8* wf = (const bf16x8*)wfragb;
  f32x4 acc0 = {0.f, 0.f, 0.f, 0.f}, acc1 = acc0, acc2 = acc0, acc3 = acc0;
  {
    bf16x8 B00 = wf[0 * 64 + l], B01 = wf[1 * 64 + l];
    bf16x8 B10 = wf[2 * 64 + l], B11 = wf[3 * 64 + l];
    bf16x8 B20 = wf[4 * 64 + l], B21 = wf[5 * 64 + l];
    bf16x8 B30 = wf[6 * 64 + l], B31 = wf[7 * 64 + l];
    acc0 = __builtin_amdgcn_mfma_f32_16x16x32_bf16(A0, B00, acc0, 0, 0, 0);
    acc0 = __builtin_amdgcn_mfma_f32_16x16x32_bf16(A1, B01, acc0, 0, 0, 0);
    acc1 = __builtin_amdgcn_mfma_f32_16x16x32_bf16(A0, B10, acc1, 0, 0, 0);
    acc1 = __builtin_amdgcn_mfma_f32_16x16x32_bf16(A1, B11, acc1, 0, 0, 0);
    acc2 = __builtin_amdgcn_mfma_f32_16x16x32_bf16(A0, B20, acc2, 0, 0, 0);
    acc2 = __builtin_amdgcn_mfma_f32_16x16x32_bf16(A1, B21, acc2, 0, 0, 0);
    acc3 = __builtin_amdgcn_mfma_f32_16x16x32_bf16(A0, B30, acc3, 0, 0, 0);
    acc3 = __builtin_amdgcn_mfma_f32_16x16x32_bf16(A1, B31, acc3, 0, 0, 0);
  }
  int c16 = l & 15, rgrp = l >> 4;
  int slot = w * 4 + rgrp;
#pragma unroll
  for (int ct = 0; ct < 4; ct++) {
    f32x4 acc = (ct == 0) ? acc0 : (ct == 1) ? acc1 : (ct == 2) ? acc2 : acc3;
    int col = ct * 16 + c16;
    float bb = b1[col];
    float cs = 0.f, cq = 0.f;
#pragma unroll
    for (int j = 0; j < 4; j++) {
      float hv = acc[j] + bb;
      int row = n0 + r0 + rgrp * 4 + j;
      h[(size_t)row * 64 + col] = (unsigned short)f2bf(hv);
      cs += hv; cq = fmaf(hv, hv, cq);
    }
    redS[slot][col] = cs;
    redQ[slot][col] = cq;
  }
  __syncthreads();
  if (tid < 64) {
    float s = 0.f, q = 0.f;
#pragma unroll
    for (int t = 0; t < 16; t++) { s += redS[t][tid]; q += redQ[t][tid]; }
    pSum[(size_t)blockIdx.x * 64 + tid] = s;
    pSq[(size_t)blockIdx.x * 64 + tid] = q;
  }
}

// ---------------- K2a: finalize BN -> affine ----------------
__global__ __launch_bounds__(256) void k_bn_final(const float* __restrict__ pSum, const float* __restrict__ pSq,
                                                  const float* __restrict__ bn_g, const float* __restrict__ bn_b,
                                                  float* __restrict__ aff) {
  int c = blockIdx.x;
  float s = 0, q = 0;
  for (int i = threadIdx.x; i < 8192; i += 256) {
    s += pSum[(size_t)i * 64 + c];
    q += pSq[(size_t)i * 64 + c];
  }
  __shared__ float rs[256], rq[256];
  rs[threadIdx.x] = s; rq[threadIdx.x] = q;
  __syncthreads();
  for (int st = 128; st > 0; st >>= 1) {
    if (threadIdx.x < st) { rs[threadIdx.x] += rs[threadIdx.x + st]; rq[threadIdx.x] += rq[threadIdx.x + st]; }
    __syncthreads();
  }
  if (threadIdx.x == 0) {
    float mu = rs[0] / (float)N_TOT;
    float var = rq[0] / (float)N_TOT - mu * mu;
    var = fmaxf(var, 0.0f);
    float A = bn_g[c] * rsqrtf(var + 1e-5f);
    aff[c] = A;
    aff[64 + c] = bn_b[c] - mu * A;
  }
}

// ---------------- K2b: LSTM step1 ----------------
__global__ __launch_bounds__(256) void k_lstm1(const float* __restrict__ bih, const float* __restrict__ bhh,
                                               const float* __restrict__ wih, const float* __restrict__ whh,
                                               float* __restrict__ q1, float* __restrict__ c1, float* __restrict__ sh2) {
  __shared__ float g1[256];
  __shared__ float q1s[64];
  int tid = threadIdx.x;
  g1[tid] = bih[tid] + bhh[tid];
  __syncthreads();
  if (tid < 64) {
    float ig = sigf(g1[tid]);
    float gg = tanhf(g1[128 + tid]);
    float cc = ig * gg;
    float og = sigf(g1[192 + tid]);
    float qv = og * tanhf(cc);
    q1s[tid] = qv; q1[tid] = qv; c1[tid] = cc;
  }
  __syncthreads();
  float acc = g1[tid];
  for (int k = 0; k < 64; k++)
    acc = fmaf(wih[(size_t)tid * 128 + k] + whh[(size_t)tid * 64 + k], q1s[k], acc);
  sh2[tid] = acc;
}

// ---------------- K3: streaming gate (no atomics) ----------------
__global__ __launch_bounds__(256) void k_gate_h(const unsigned short* __restrict__ h, const float* __restrict__ aff,
                                                const float* __restrict__ w2, const float* __restrict__ cb2,
                                                const float* __restrict__ eps_gate,
                                                float* __restrict__ lamWS, float* __restrict__ lamOut,
                                                int* __restrict__ presPart) {
  __shared__ float Hs[64][65];
  __shared__ float A2s[64], C2s[64], w2s[64];
  __shared__ int pcnt[4];
  int tid = threadIdx.x;
  if (tid < 64) { A2s[tid] = aff[tid]; C2s[tid] = aff[64 + tid]; w2s[tid] = w2[tid]; }
  int n0 = blockIdx.x * 64;
#pragma unroll
  for (int s = 0; s < 4; s++) {
    int e4 = tid * 4 + s * 1024;
    int r = e4 >> 6, c = e4 & 63;
    ushort4 v = *(const ushort4*)&h[(size_t)(n0 + r) * 64 + c];
    Hs[r][c] = bf2f(v.x); Hs[r][c + 1] = bf2f(v.y);
    Hs[r][c + 2] = bf2f(v.z); Hs[r][c + 3] = bf2f(v.w);
  }
  __syncthreads();
  int r = tid >> 2, q = tid & 3;
  float p = 0.f;
#pragma unroll
  for (int j = 0; j < 16; j++) {
    int d = q * 16 + j;
    p = fmaf(fmaxf(fmaf(Hs[r][d], A2s[d], C2s[d]), 0.f), w2s[d], p);
  }
  p += __shfl_xor(p, 1);
  p += __shfl_xor(p, 2);
  p += cb2[0];
  unsigned long long m = __ballot(q == 0 && p > 0.0f);
  if ((tid & 63) == 0) pcnt[tid >> 6] = (int)__popcll(m);
  if (q == 0) {
    int row = n0 + r;
    float eg = eps_gate[row];
    float eps = 0.9999f - 0.9998f * eg;
    float gi = (flog2(eps) - flog2(1.0f - eps)) * LN2;
    float lam = sigf(gi + p);
    lamWS[row] = lam;
    lamOut[row] = lam;
  }
  __syncthreads();
  if (tid == 0) presPart[blockIdx.x] = pcnt[0] + pcnt[1] + pcnt[2] + pcnt[3];
}

// ---------------- K4: register-resident wave-per-graph, batched attention ----------------
__global__ __launch_bounds__(256) void k_graph_reg(const float* __restrict__ X, const float* __restrict__ noise,
                                                   const float* __restrict__ lam, const int* __restrict__ off,
                                                   const float* __restrict__ q1g, const float* __restrict__ c1g,
                                                   const float* __restrict__ sh2g, const float* __restrict__ rtg,
                                                   unsigned short* __restrict__ noisyFB, float* __restrict__ qstar,
                                                   float* __restrict__ klp) {
  int wg = blockIdx.x * 4 + (threadIdx.x >> 6);
  int lane = threadIdx.x & 63;
  int n0 = off[wg], cnt = off[wg + 1] - n0;
  const float THR = 8.f;
  const float* xp = X + (size_t)n0 * 64 + lane;
  const float* zp = noise + (size_t)n0 * 64 + lane;
  float r1v = 0.f;
  bool fits = (cnt <= CAPR);
  unsigned int pk[CAPR / 2];

  if (cnt > 0 && fits) {
    // ---- pass 1: X stats (f32-exact), stash bf16 X in regs; zero unused regs ----
    float s0 = 0.f, q0 = 0.f, s1 = 0.f, q1_ = 0.f;
#pragma unroll
    for (int np = 0; np < CAPR / 2; np++) {
      int n = 2 * np;
      if (n < cnt) {
        float a = xp[(size_t)n * 64];
        s0 += a; q0 = fmaf(a, a, q0);
        float b = 0.f;
        if (n + 1 < cnt) {
          b = xp[(size_t)(n + 1) * 64];
          s1 += b; q1_ = fmaf(b, b, q1_);
        }
        pk[np] = (f2bf(b) << 16) | f2bf(a);
      } else {
        pk[np] = 0u;   // keep multi-reduce NaN-free
      }
    }
    float c = (float)cnt;
    float mean = (s0 + s1) / c;
    float var = fmaxf(((q0 + q1_) - c * mean * mean) / fmaxf(c - 1.f, 1.f), 0.f);
    float sd = sqrtf(var);
    float inv = frcp(sd + 1e-7f);
    float S1 = wave_red(sd * sd * inv * inv);
    // ---- pass 2: noisy (bf16 into SAME regs) + KL partials; NO attention here ----
    float t2acc = 0.f, sumOm2 = 0.f;
#pragma unroll
    for (int np = 0; np < CAPR / 2; np++) {
      int n = 2 * np;
      if (n < cnt) {
        bool hasB = (n + 1 < cnt);
        unsigned int p2 = pk[np];
        float xA = bf2f(p2 & 0xffffu), xB = bf2f(p2 >> 16);
        float lamA = lam[n0 + n];
        float zA = zp[(size_t)n * 64];
        float lamB = hasB ? lam[n0 + n + 1] : 0.f;
        float zB = hasB ? zp[(size_t)(n + 1) * 64] : 0.f;
        float omA = 1.f - lamA, omB = 1.f - lamB;
        float nvA = fmaf(lamA, xA, omA * mean) + zA * (omA * sd);
        float nvB = fmaf(lamB, xB, omB * mean) + zB * (omB * sd);
        pk[np] = hasB ? ((f2bf(nvB) << 16) | f2bf(nvA)) : f2bf(nvA);  // invalid hi slot -> 0
        float ldA = lamA * (xA - mean) * inv; t2acc = fmaf(ldA, ldA, t2acc);
        sumOm2 = fmaf(omA, omA, sumOm2);
        if (hasB) {
          float ldB = lamB * (xB - mean) * inv; t2acc = fmaf(ldB, ldB, t2acc);
          sumOm2 = fmaf(omB, omB, sumOm2);
        }
      }
    }
    // ---- attention step 1: batched multi-reduce softmax ----
    r1v = attn_batched(pk, cnt, q1g[lane] * LOG2E, lane);
    float t2tot = wave_red(t2acc);
    if (lane == 0) klp[wg] = fmaf(0.5f * sumOm2, S1, t2tot);
  } else if (cnt > 0) {
    // ---- fallback (cnt > CAPR): global-memory online-softmax path ----
    unsigned short* nw = noisyFB + (size_t)n0 * 64 + lane;
    float s0 = 0.f, q0 = 0.f;
    for (int n = 0; n < cnt; n++) { float a = xp[(size_t)n * 64]; s0 += a; q0 = fmaf(a, a, q0); }
    float c = (float)cnt;
    float mean = s0 / c;
    float var = fmaxf((q0 - c * mean * mean) / fmaxf(c - 1.f, 1.f), 0.f);
    float sd = sqrtf(var);
    float inv = frcp(sd + 1e-7f);
    float S1 = wave_red(sd * sd * inv * inv);
    float q1v2 = q1g[lane] * LOG2E;
    float t2acc = 0.f, sumOm2 = 0.f;
    float m0 = -INFINITY, l0 = 0.f, r0 = 0.f;
    for (int n = 0; n < cnt; n++) {
      float lamA = lam[n0 + n];
      float xA = xp[(size_t)n * 64];
      float zA = zp[(size_t)n * 64];
      float omA = 1.f - lamA;
      float nvA = fmaf(lamA, xA, omA * mean) + zA * (omA * sd);
      nw[(size_t)n * 64] = (unsigned short)f2bf(nvA);
      float ldA = lamA * (xA - mean) * inv; t2acc = fmaf(ldA, ldA, t2acc);
      sumOm2 = fmaf(omA, omA, sumOm2);
      float e0 = wave_red(nvA * q1v2);
      if (e0 > m0 + THR) { float sc = fexp2(m0 - e0); l0 *= sc; r0 *= sc; m0 = e0; }
      float pA = fexp2(e0 - m0); l0 += pA; r0 = fmaf(pA, nvA, r0);
    }
    r1v = r0 / l0;
    float t2tot = wave_red(t2acc);
    if (lane == 0) klp[wg] = fmaf(0.5f * sumOm2, S1, t2tot);
  } else {
    if (lane == 0) klp[wg] = 0.0f;
  }

  // ---- fused LSTM step 2 ----
  float a0 = 0.f, a1 = 0.f, a2 = 0.f, a3 = 0.f;
  const float4* rt = (const float4*)rtg;
#pragma unroll 4
  for (int k = 0; k < 64; k++) {
    float rk = __shfl(r1v, k);
    float4 w = rt[k * 64 + lane];
    a0 = fmaf(w.x, rk, a0); a1 = fmaf(w.y, rk, a1);
    a2 = fmaf(w.z, rk, a2); a3 = fmaf(w.w, rk, a3);
  }
  float ig = a0 + sh2g[lane];
  float fg = a1 + sh2g[64 + lane];
  float gg = a2 + sh2g[128 + lane];
  float og = a3 + sh2g[192 + lane];
  float c2 = sigf(fg) * c1g[lane] + sigf(ig) * tanhf(gg);
  float q2 = sigf(og) * tanhf(c2);
  qstar[(size_t)wg * 128 + lane] = q2;

  // ---- attention step 2 ----
  float r2v = 0.f;
  if (cnt > 0) {
    float q2v2 = q2 * LOG2E;
    if (fits) {
      r2v = attn_batched(pk, cnt, q2v2, lane);
    } else {
      const float THR2 = 8.f;
      const unsigned short* np_ = noisyFB + (size_t)n0 * 64 + lane;
      float m0 = -INFINITY, l0 = 0.f, r0 = 0.f;
      for (int n = 0; n < cnt; n++) {
        float nvA = bf2f(np_[(size_t)n * 64]);
        float e0 = wave_red(nvA * q2v2);
        if (e0 > m0 + THR2) { float sc = fexp2(m0 - e0); l0 *= sc; r0 *= sc; m0 = e0; }
        float pA = fexp2(e0 - m0); l0 += pA; r0 = fmaf(pA, nvA, r0);
      }
      r2v = r0 / l0;
    }
  }
  qstar[(size_t)wg * 128 + 64 + lane] = r2v;
}

// ---------------- K7/8/9: predictor linear layers ----------------
template <int KDIM, int ODIM, bool RELU>
__global__ __launch_bounds__(256) void k_linear(const float* __restrict__ A, const float* __restrict__ WT,
                                                const float* __restrict__ bias, float* __restrict__ C) {
  __shared__ float As[64][68];
  __shared__ float Wt[64][68];
  int tid = threadIdx.x, ty = tid >> 4, tx = tid & 15;
  int n0 = blockIdx.x * 64, c0 = blockIdx.y * 64;
  float acc[4][4] = {};
  for (int kt = 0; kt < KDIM; kt += 64) {
    __syncthreads();
    load_A64(A, KDIM, n0, kt, As, tid);
    load_A64(WT, ODIM, kt, c0, Wt, tid);
    __syncthreads();
    mm64(As, Wt, ty, tx, acc);
  }
#pragma unroll
  for (int i = 0; i < 4; i++) {
    int row = n0 + ty * 4 + i;
    float4 o;
    float v0 = acc[i][0] + bias[c0 + tx * 4 + 0];
    float v1 = acc[i][1] + bias[c0 + tx * 4 + 1];
    float v2 = acc[i][2] + bias[c0 + tx * 4 + 2];
    float v3 = acc[i][3] + bias[c0 + tx * 4 + 3];
    if (RELU) { v0 = fmaxf(v0, 0.f); v1 = fmaxf(v1, 0.f); v2 = fmaxf(v2, 0.f); v3 = fmaxf(v3, 0.f); }
    o.x = v0; o.y = v1; o.z = v2; o.w = v3;
    *(float4*)&C[(size_t)row * ODIM + c0 + tx * 4] = o;
  }
}

// ---------------- K10: final scalars ----------------
__global__ __launch_bounds__(256) void k_final(const float* __restrict__ klp, const int* __restrict__ presPart,
                                               float* __restrict__ out) {
  __shared__ float red[256];
  __shared__ int redi[256];
  float s = 0.0f;
  int pc = 0;
  for (int i = threadIdx.x; i < B_GR; i += 256) s += klp[i];
  for (int i = threadIdx.x; i < 8192; i += 256) pc += presPart[i];
  red[threadIdx.x] = s;
  redi[threadIdx.x] = pc;
  __syncthreads();
  for (int st = 128; st > 0; st >>= 1) {
    if (threadIdx.x < st) {
      red[threadIdx.x] += red[threadIdx.x + st];
      redi[threadIdx.x] += redi[threadIdx.x + st];
    }
    __syncthreads();
  }
  if (threadIdx.x == 0) {
    out[(size_t)B_GR * 64] = red[0] / (float)(B_GR * 64);
    out[(size_t)B_GR * 64 + 1] = (float)redi[0] / (float)N_TOT;
  }
}

// ---------------- launcher ----------------
extern "C" void kernel_launch(void* const* d_in, const int* in_sizes, int n_in,
                              void* d_out, int out_size, void* d_ws, size_t ws_size,
                              hipStream_t stream) {
  const float* features = (const float*)d_in[0];
  const int*   bidx     = (const int*)d_in[1];
  const float* eps_gate = (const float*)d_in[2];
  const float* noise    = (const float*)d_in[3];
  const float* c_w1 = (const float*)d_in[4];
  const float* c_b1 = (const float*)d_in[5];
  const float* bn_g = (const float*)d_in[6];
  const float* bn_b = (const float*)d_in[7];
  const float* c_w2 = (const float*)d_in[8];
  const float* c_b2 = (const float*)d_in[9];
  const float* wih  = (const float*)d_in[10];
  const float* whh  = (const float*)d_in[11];
  const float* bih  = (const float*)d_in[12];
  const float* bhh  = (const float*)d_in[13];
  const float* p_w1 = (const float*)d_in[14];
  const float* p_b1 = (const float*)d_in[15];
  const float* p_w2 = (const float*)d_in[16];
  const float* p_b2 = (const float*)d_in[17];
  const float* p_w3 = (const float*)d_in[18];
  const float* p_b3 = (const float*)d_in[19];
  float* out = (float*)d_out;

  float* wsf   = (float*)d_ws;
  int*   offp  = (int*)wsf;                                 // (B+1) ints
  float* pSum  = wsf + 16448;                               // 8192*64
  float* pSq   = pSum + 524288;                             // 8192*64
  float* aff   = pSq + 524288;                              // 128
  float* q1w   = aff + 128;                                 // 64
  float* c1w   = q1w + 64;                                  // 64
  float* sh2w  = c1w + 64;                                  // 256
  float* lamw  = sh2w + 256;                                // N
  float* pw1T  = lamw + (size_t)N_TOT;                      // 128*256
  float* pw2T  = pw1T + 32768;                              // 256*128
  float* pw3T  = pw2T + 32768;                              // 128*64
  float* rtgw  = pw3T + 8192;                               // 64*256 (RTg)
  unsigned short* wfragb = (unsigned short*)(rtgw + 16384); // 8*64*8 ushorts
  float* hwf   = rtgw + 16384 + 2048;                       // N*64 region
  unsigned short* hb = (unsigned short*)hwf;                // h bf16; reused as noisy fallback
  unsigned short* noisyFB = hb;
  float* qstarw = hwf + (size_t)N_TOT * 64;                 // B*128
  float* z1w    = qstarw + (size_t)B_GR * 128;              // B*256
  float* z2w    = z1w + (size_t)B_GR * 256;                 // B*128
  float* klpw   = z2w + (size_t)B_GR * 128;                 // B
  int*   presPart = (int*)(klpw + B_GR);                    // 8192 ints

  float* lamOut = out + (size_t)B_GR * 64 + 2;

  k_offsets<<<(B_GR + 1 + 255) / 256, 256, 0, stream>>>(bidx, offp);
  k_prep<<<64, 256, 0, stream>>>(c_w1, p_w1, p_w2, p_w3, wih, pw1T, pw2T, pw3T, rtgw, wfragb);
  k_bn_stats<<<N_TOT / 64, 256, 0, stream>>>(features, wfragb, c_b1, hb, pSum, pSq);
  k_bn_final<<<64, 256, 0, stream>>>(pSum, pSq, bn_g, bn_b, aff);
  k_lstm1<<<1, 256, 0, stream>>>(bih, bhh, wih, whh, q1w, c1w, sh2w);
  k_gate_h<<<N_TOT / 64, 256, 0, stream>>>(hb, aff, c_w2, c_b2, eps_gate, lamw, lamOut, presPart);
  k_graph_reg<<<B_GR / 4, 256, 0, stream>>>(features, noise, lamw, offp, q1w, c1w, sh2w, rtgw,
                                            noisyFB, qstarw, klpw);
  k_linear<128, 256, true><<<dim3(B_GR / 64, 4), 256, 0, stream>>>(qstarw, pw1T, p_b1, z1w);
  k_linear<256, 128, true><<<dim3(B_GR / 64, 2), 256, 0, stream>>>(z1w, pw2T, p_b2, z2w);
  k_linear<128, 64, false><<<dim3(B_GR / 64, 1), 256, 0, stream>>>(z2w, pw3T, p_b3, out);
  k_final<<<1, 256, 0, stream>>>(klpw, presPart, out);
}

// Round 15
// 260.808 us; speedup vs baseline: 1.4108x; 1.4108x over previous
//
#include <hip/hip_runtime.h>
#include <math.h>

#define N_TOT 524288
#define B_GR  16384
#define CAPR  64

#define LOG2E 1.44269504088896f
#define LN2   0.69314718055995f

typedef __attribute__((ext_vector_type(8))) short bf16x8;
typedef __attribute__((ext_vector_type(4))) float f32x4;

// ---------------- small device helpers ----------------
__device__ __forceinline__ float fexp2(float x) { return __builtin_amdgcn_exp2f(x); }
__device__ __forceinline__ float flog2(float x) { return __builtin_amdgcn_logf(x); }
__device__ __forceinline__ float frcp(float x)  { return __builtin_amdgcn_rcpf(x); }
__device__ __forceinline__ float sigf(float x)  { return frcp(1.0f + fexp2(-x * LOG2E)); }

// bf16 pack/unpack (RNE)
__device__ __forceinline__ unsigned int f2bf(float x) {
  unsigned int u = __float_as_uint(x);
  return (u + 0x7FFFu + ((u >> 16) & 1u)) >> 16;
}
__device__ __forceinline__ float bf2f(unsigned int s) {
  return __uint_as_float(s << 16);
}

// ---- DPP-based 64-lane sum ----
template <int CTRL>
__device__ __forceinline__ float dppadd(float v) {
  return v + __int_as_float(__builtin_amdgcn_update_dpp(
      0, __float_as_int(v), CTRL, 0xF, 0xF, true));
}
__device__ __forceinline__ float wave_red(float v) {
  v = dppadd<0x111>(v);   // row_shr:1
  v = dppadd<0x112>(v);   // row_shr:2
  v = dppadd<0x114>(v);   // row_shr:4
  v = dppadd<0x118>(v);   // row_shr:8
  v = dppadd<0x142>(v);   // row_bcast15
  v = dppadd<0x143>(v);   // row_bcast31
  return __int_as_float(__builtin_amdgcn_readlane(__float_as_int(v), 63));
}

// ---------------- K0a: graph offsets ----------------
__global__ void k_offsets(const int* __restrict__ idx, int* __restrict__ off) {
  int b = blockIdx.x * blockDim.x + threadIdx.x;
  if (b > B_GR) return;
  if (b == B_GR) { off[B_GR] = N_TOT; return; }
  int lo = 0, hi = N_TOT;
  while (lo < hi) { int mid = (lo + hi) >> 1; if (idx[mid] < b) lo = mid + 1; else hi = mid; }
  off[b] = lo;
}

// ---------------- K0b: RTg for fused LSTM2; bf16 MFMA B-fragments for all GEMMs ----------------
// Fragment layout (validated by k_bn_stats): frag f = ct*NKF + kt; lane l, elem j:
//   k = kt*32 + (l>>4)*8 + j,  col = ct*16 + (l&15),  value = W[col][k]  (W row-major [O][K]).
__global__ void k_prep(const float* __restrict__ w1, const float* __restrict__ pw1,
                       const float* __restrict__ pw2, const float* __restrict__ pw3,
                       const float* __restrict__ wih,
                       float* __restrict__ rtg, unsigned short* __restrict__ wfragb,
                       unsigned short* __restrict__ wf1, unsigned short* __restrict__ wf2,
                       unsigned short* __restrict__ wf3) {
  int t = blockIdx.x * 256 + threadIdx.x;
  for (int i = t; i < 64 * 64 * 4; i += 16384) {
    int k = i >> 8, rem = i & 255, d = rem >> 2, j = rem & 3;
    rtg[i] = wih[(size_t)(j * 64 + d) * 128 + 64 + k];
  }
  // w1 (compressor, K=64, O=64): NKF=2, NCT=4, frag f = ct*2 + kt
  for (int i = t; i < 8 * 64 * 8; i += 16384) {
    int f = i >> 9, lane = (i >> 3) & 63, j = i & 7;
    int ct = f >> 1, kt = f & 1;
    int k = kt * 32 + (lane >> 4) * 8 + j;
    int col = ct * 16 + (lane & 15);
    wfragb[i] = (unsigned short)f2bf(w1[(size_t)col * 64 + k]);
  }
  // p_w1 (K=128, O=256): NKF=4, NCT=16 -> 64 frags
  for (int i = t; i < 64 * 64 * 8; i += 16384) {
    int f = i >> 9, lane = (i >> 3) & 63, j = i & 7;
    int ct = f >> 2, kt = f & 3;
    int k = kt * 32 + (lane >> 4) * 8 + j;
    int col = ct * 16 + (lane & 15);
    wf1[i] = (unsigned short)f2bf(pw1[(size_t)col * 128 + k]);
  }
  // p_w2 (K=256, O=128): NKF=8, NCT=8 -> 64 frags
  for (int i = t; i < 64 * 64 * 8; i += 16384) {
    int f = i >> 9, lane = (i >> 3) & 63, j = i & 7;
    int ct = f >> 3, kt = f & 7;
    int k = kt * 32 + (lane >> 4) * 8 + j;
    int col = ct * 16 + (lane & 15);
    wf2[i] = (unsigned short)f2bf(pw2[(size_t)col * 256 + k]);
  }
  // p_w3 (K=128, O=64): NKF=4, NCT=4 -> 16 frags
  for (int i = t; i < 16 * 64 * 8; i += 16384) {
    int f = i >> 9, lane = (i >> 3) & 63, j = i & 7;
    int ct = f >> 2, kt = f & 3;
    int k = kt * 32 + (lane >> 4) * 8 + j;
    int col = ct * 16 + (lane & 15);
    wf3[i] = (unsigned short)f2bf(pw3[(size_t)col * 128 + k]);
  }
}

// ---------------- K1: MFMA h = X@W1^T + b1 -> bf16 h; stats partials ----------------
__global__ __launch_bounds__(256) void k_bn_stats(const float* __restrict__ X,
                                                  const unsigned short* __restrict__ wfragb,
                                                  const float* __restrict__ b1, unsigned short* __restrict__ h,
                                                  float* __restrict__ pSum, float* __restrict__ pSq) {
  __shared__ float redS[16][64];
  __shared__ float redQ[16][64];
  int tid = threadIdx.x, w = tid >> 6, l = tid & 63;
  int n0 = blockIdx.x * 64;
  int r0 = w * 16;
  int arow = n0 + r0 + (l & 15);
  int kb = (l >> 4) * 8;
  const float* xr = X + (size_t)arow * 64 + kb;
  float4 a00 = *(const float4*)&xr[0];
  float4 a01 = *(const float4*)&xr[4];
  float4 a10 = *(const float4*)&xr[32];
  float4 a11 = *(const float4*)&xr[36];
  bf16x8 A0, A1;
  A0[0] = (short)f2bf(a00.x); A0[1] = (short)f2bf(a00.y); A0[2] = (short)f2bf(a00.z); A0[3] = (short)f2bf(a00.w);
  A0[4] = (short)f2bf(a01.x); A0[5] = (short)f2bf(a01.y); A0[6] = (short)f2bf(a01.z); A0[7] = (short)f2bf(a01.w);
  A1[0] = (short)f2bf(a10.x); A1[1] = (short)f2bf(a10.y); A1[2] = (short)f2bf(a10.z); A1[3] = (short)f2bf(a10.w);
  A1[4] = (short)f2bf(a11.x); A1[5] = (short)f2bf(a11.y); A1[6] = (short)f2bf(a11.z); A1[7] = (short)f2bf(a11.w);
  const bf16x8* wf = (const bf16x8*)wfragb;
  f32x4 acc0 = {0.f, 0.f, 0.f, 0.f}, acc1 = acc0, acc2 = acc0, acc3 = acc0;
  {
    bf16x8 B00 = wf[0 * 64 + l], B01 = wf[1 * 64 + l];
    bf16x8 B10 = wf[2 * 64 + l], B11 = wf[3 * 64 + l];
    bf16x8 B20 = wf[4 * 64 + l], B21 = wf[5 * 64 + l];
    bf16x8 B30 = wf[6 * 64 + l], B31 = wf[7 * 64 + l];
    acc0 = __builtin_amdgcn_mfma_f32_16x16x32_bf16(A0, B00, acc0, 0, 0, 0);
    acc0 = __builtin_amdgcn_mfma_f32_16x16x32_bf16(A1, B01, acc0, 0, 0, 0);
    acc1 = __builtin_amdgcn_mfma_f32_16x16x32_bf16(A0, B10, acc1, 0, 0, 0);
    acc1 = __builtin_amdgcn_mfma_f32_16x16x32_bf16(A1, B11, acc1, 0, 0, 0);
    acc2 = __builtin_amdgcn_mfma_f32_16x16x32_bf16(A0, B20, acc2, 0, 0, 0);
    acc2 = __builtin_amdgcn_mfma_f32_16x16x32_bf16(A1, B21, acc2, 0, 0, 0);
    acc3 = __builtin_amdgcn_mfma_f32_16x16x32_bf16(A0, B30, acc3, 0, 0, 0);
    acc3 = __builtin_amdgcn_mfma_f32_16x16x32_bf16(A1, B31, acc3, 0, 0, 0);
  }
  int c16 = l & 15, rgrp = l >> 4;
  int slot = w * 4 + rgrp;
#pragma unroll
  for (int ct = 0; ct < 4; ct++) {
    f32x4 acc = (ct == 0) ? acc0 : (ct == 1) ? acc1 : (ct == 2) ? acc2 : acc3;
    int col = ct * 16 + c16;
    float bb = b1[col];
    float cs = 0.f, cq = 0.f;
#pragma unroll
    for (int j = 0; j < 4; j++) {
      float hv = acc[j] + bb;
      int row = n0 + r0 + rgrp * 4 + j;
      h[(size_t)row * 64 + col] = (unsigned short)f2bf(hv);
      cs += hv; cq = fmaf(hv, hv, cq);
    }
    redS[slot][col] = cs;
    redQ[slot][col] = cq;
  }
  __syncthreads();
  if (tid < 64) {
    float s = 0.f, q = 0.f;
#pragma unroll
    for (int t = 0; t < 16; t++) { s += redS[t][tid]; q += redQ[t][tid]; }
    pSum[(size_t)blockIdx.x * 64 + tid] = s;
    pSq[(size_t)blockIdx.x * 64 + tid] = q;
  }
}

// ---------------- K2a: finalize BN -> affine ----------------
__global__ __launch_bounds__(256) void k_bn_final(const float* __restrict__ pSum, const float* __restrict__ pSq,
                                                  const float* __restrict__ bn_g, const float* __restrict__ bn_b,
                                                  float* __restrict__ aff) {
  int c = blockIdx.x;
  float s = 0, q = 0;
  for (int i = threadIdx.x; i < 8192; i += 256) {
    s += pSum[(size_t)i * 64 + c];
    q += pSq[(size_t)i * 64 + c];
  }
  __shared__ float rs[256], rq[256];
  rs[threadIdx.x] = s; rq[threadIdx.x] = q;
  __syncthreads();
  for (int st = 128; st > 0; st >>= 1) {
    if (threadIdx.x < st) { rs[threadIdx.x] += rs[threadIdx.x + st]; rq[threadIdx.x] += rq[threadIdx.x + st]; }
    __syncthreads();
  }
  if (threadIdx.x == 0) {
    float mu = rs[0] / (float)N_TOT;
    float var = rq[0] / (float)N_TOT - mu * mu;
    var = fmaxf(var, 0.0f);
    float A = bn_g[c] * rsqrtf(var + 1e-5f);
    aff[c] = A;
    aff[64 + c] = bn_b[c] - mu * A;
  }
}

// ---------------- K2b: LSTM step1 ----------------
__global__ __launch_bounds__(256) void k_lstm1(const float* __restrict__ bih, const float* __restrict__ bhh,
                                               const float* __restrict__ wih, const float* __restrict__ whh,
                                               float* __restrict__ q1, float* __restrict__ c1, float* __restrict__ sh2) {
  __shared__ float g1[256];
  __shared__ float q1s[64];
  int tid = threadIdx.x;
  g1[tid] = bih[tid] + bhh[tid];
  __syncthreads();
  if (tid < 64) {
    float ig = sigf(g1[tid]);
    float gg = tanhf(g1[128 + tid]);
    float cc = ig * gg;
    float og = sigf(g1[192 + tid]);
    float qv = og * tanhf(cc);
    q1s[tid] = qv; q1[tid] = qv; c1[tid] = cc;
  }
  __syncthreads();
  float acc = g1[tid];
  for (int k = 0; k < 64; k++)
    acc = fmaf(wih[(size_t)tid * 128 + k] + whh[(size_t)tid * 64 + k], q1s[k], acc);
  sh2[tid] = acc;
}

// ---------------- K3: streaming gate (no atomics) ----------------
__global__ __launch_bounds__(256) void k_gate_h(const unsigned short* __restrict__ h, const float* __restrict__ aff,
                                                const float* __restrict__ w2, const float* __restrict__ cb2,
                                                const float* __restrict__ eps_gate,
                                                float* __restrict__ lamWS, float* __restrict__ lamOut,
                                                int* __restrict__ presPart) {
  __shared__ float Hs[64][65];
  __shared__ float A2s[64], C2s[64], w2s[64];
  __shared__ int pcnt[4];
  int tid = threadIdx.x;
  if (tid < 64) { A2s[tid] = aff[tid]; C2s[tid] = aff[64 + tid]; w2s[tid] = w2[tid]; }
  int n0 = blockIdx.x * 64;
#pragma unroll
  for (int s = 0; s < 4; s++) {
    int e4 = tid * 4 + s * 1024;
    int r = e4 >> 6, c = e4 & 63;
    ushort4 v = *(const ushort4*)&h[(size_t)(n0 + r) * 64 + c];
    Hs[r][c] = bf2f(v.x); Hs[r][c + 1] = bf2f(v.y);
    Hs[r][c + 2] = bf2f(v.z); Hs[r][c + 3] = bf2f(v.w);
  }
  __syncthreads();
  int r = tid >> 2, q = tid & 3;
  float p = 0.f;
#pragma unroll
  for (int j = 0; j < 16; j++) {
    int d = q * 16 + j;
    p = fmaf(fmaxf(fmaf(Hs[r][d], A2s[d], C2s[d]), 0.f), w2s[d], p);
  }
  p += __shfl_xor(p, 1);
  p += __shfl_xor(p, 2);
  p += cb2[0];
  unsigned long long m = __ballot(q == 0 && p > 0.0f);
  if ((tid & 63) == 0) pcnt[tid >> 6] = (int)__popcll(m);
  if (q == 0) {
    int row = n0 + r;
    float eg = eps_gate[row];
    float eps = 0.9999f - 0.9998f * eg;
    float gi = (flog2(eps) - flog2(1.0f - eps)) * LN2;
    float lam = sigf(gi + p);
    lamWS[row] = lam;
    lamOut[row] = lam;
  }
  __syncthreads();
  if (tid == 0) presPart[blockIdx.x] = pcnt[0] + pcnt[1] + pcnt[2] + pcnt[3];
}

// ---------------- K4: register-resident wave-per-graph (R13 structure), bf16 qstar out ----------------
__global__ __launch_bounds__(256) void k_graph_reg(const float* __restrict__ X, const float* __restrict__ noise,
                                                   const float* __restrict__ lam, const int* __restrict__ off,
                                                   const float* __restrict__ q1g, const float* __restrict__ c1g,
                                                   const float* __restrict__ sh2g, const float* __restrict__ rtg,
                                                   unsigned short* __restrict__ noisyFB, unsigned short* __restrict__ qstarb,
                                                   float* __restrict__ klp) {
  int wg = blockIdx.x * 4 + (threadIdx.x >> 6);
  int lane = threadIdx.x & 63;
  int n0 = off[wg], cnt = off[wg + 1] - n0;
  const float THR = 8.f;
  const float* xp = X + (size_t)n0 * 64 + lane;
  const float* zp = noise + (size_t)n0 * 64 + lane;
  float r1v = 0.f;
  bool fits = (cnt <= CAPR);
  unsigned int pk[CAPR / 2];

  if (cnt > 0 && fits) {
    float s0 = 0.f, q0 = 0.f, s1 = 0.f, q1_ = 0.f;
#pragma unroll
    for (int np = 0; np < CAPR / 2; np++) {
      int n = 2 * np;
      if (n < cnt) {
        float a = xp[(size_t)n * 64];
        s0 += a; q0 = fmaf(a, a, q0);
        float b = 0.f;
        if (n + 1 < cnt) {
          b = xp[(size_t)(n + 1) * 64];
          s1 += b; q1_ = fmaf(b, b, q1_);
        }
        pk[np] = (f2bf(b) << 16) | f2bf(a);
      }
    }
    float c = (float)cnt;
    float mean = (s0 + s1) / c;
    float var = fmaxf(((q0 + q1_) - c * mean * mean) / fmaxf(c - 1.f, 1.f), 0.f);
    float sd = sqrtf(var);
    float inv = frcp(sd + 1e-7f);
    float S1 = wave_red(sd * sd * inv * inv);
    float q1v2 = q1g[lane] * LOG2E;
    float t2acc = 0.f, sumOm2 = 0.f;
    float m0 = -INFINITY, l0 = 0.f, r0 = 0.f;
    float m1 = -INFINITY, l1 = 0.f, r1a = 0.f;
#pragma unroll
    for (int np = 0; np < CAPR / 2; np++) {
      int n = 2 * np;
      if (n < cnt) {
        bool hasB = (n + 1 < cnt);
        unsigned int p2 = pk[np];
        float xA = bf2f(p2 & 0xffffu), xB = bf2f(p2 >> 16);
        float lamA = lam[n0 + n];
        float zA = zp[(size_t)n * 64];
        float lamB = hasB ? lam[n0 + n + 1] : 0.f;
        float zB = hasB ? zp[(size_t)(n + 1) * 64] : 0.f;
        float omA = 1.f - lamA, omB = 1.f - lamB;
        float nvA = fmaf(lamA, xA, omA * mean) + zA * (omA * sd);
        float nvB = fmaf(lamB, xB, omB * mean) + zB * (omB * sd);
        pk[np] = (f2bf(nvB) << 16) | f2bf(nvA);
        float ldA = lamA * (xA - mean) * inv; t2acc = fmaf(ldA, ldA, t2acc);
        sumOm2 = fmaf(omA, omA, sumOm2);
        if (hasB) {
          float ldB = lamB * (xB - mean) * inv; t2acc = fmaf(ldB, ldB, t2acc);
          sumOm2 = fmaf(omB, omB, sumOm2);
        }
        float e0 = wave_red(nvA * q1v2);
        float e1 = hasB ? wave_red(nvB * q1v2) : 0.f;
        if (e0 > m0 + THR) { float sc = fexp2(m0 - e0); l0 *= sc; r0 *= sc; m0 = e0; }
        float pA = fexp2(e0 - m0); l0 += pA; r0 = fmaf(pA, nvA, r0);
        if (hasB) {
          if (e1 > m1 + THR) { float sc = fexp2(m1 - e1); l1 *= sc; r1a *= sc; m1 = e1; }
          float pB = fexp2(e1 - m1); l1 += pB; r1a = fmaf(pB, nvB, r1a);
        }
      }
    }
    float M = fmaxf(m0, m1);
    float sc0 = fexp2(m0 - M), sc1 = (m1 == -INFINITY) ? 0.f : fexp2(m1 - M);
    float L = l0 * sc0 + l1 * sc1;
    float R = r0 * sc0 + r1a * sc1;
    r1v = R / L;
    float t2tot = wave_red(t2acc);
    if (lane == 0) klp[wg] = fmaf(0.5f * sumOm2, S1, t2tot);
  } else if (cnt > 0) {
    unsigned short* nw = noisyFB + (size_t)n0 * 64 + lane;
    float s0 = 0.f, q0 = 0.f;
    for (int n = 0; n < cnt; n++) { float a = xp[(size_t)n * 64]; s0 += a; q0 = fmaf(a, a, q0); }
    float c = (float)cnt;
    float mean = s0 / c;
    float var = fmaxf((q0 - c * mean * mean) / fmaxf(c - 1.f, 1.f), 0.f);
    float sd = sqrtf(var);
    float inv = frcp(sd + 1e-7f);
    float S1 = wave_red(sd * sd * inv * inv);
    float q1v2 = q1g[lane] * LOG2E;
    float t2acc = 0.f, sumOm2 = 0.f;
    float m0 = -INFINITY, l0 = 0.f, r0 = 0.f;
    for (int n = 0; n < cnt; n++) {
      float lamA = lam[n0 + n];
      float xA = xp[(size_t)n * 64];
      float zA = zp[(size_t)n * 64];
      float omA = 1.f - lamA;
      float nvA = fmaf(lamA, xA, omA * mean) + zA * (omA * sd);
      nw[(size_t)n * 64] = (unsigned short)f2bf(nvA);
      float ldA = lamA * (xA - mean) * inv; t2acc = fmaf(ldA, ldA, t2acc);
      sumOm2 = fmaf(omA, omA, sumOm2);
      float e0 = wave_red(nvA * q1v2);
      if (e0 > m0 + THR) { float sc = fexp2(m0 - e0); l0 *= sc; r0 *= sc; m0 = e0; }
      float pA = fexp2(e0 - m0); l0 += pA; r0 = fmaf(pA, nvA, r0);
    }
    r1v = r0 / l0;
    float t2tot = wave_red(t2acc);
    if (lane == 0) klp[wg] = fmaf(0.5f * sumOm2, S1, t2tot);
  } else {
    if (lane == 0) klp[wg] = 0.0f;
  }

  // ---- fused LSTM step 2 ----
  float a0 = 0.f, a1 = 0.f, a2 = 0.f, a3 = 0.f;
  const float4* rt = (const float4*)rtg;
#pragma unroll 4
  for (int k = 0; k < 64; k++) {
    float rk = __shfl(r1v, k);
    float4 w = rt[k * 64 + lane];
    a0 = fmaf(w.x, rk, a0); a1 = fmaf(w.y, rk, a1);
    a2 = fmaf(w.z, rk, a2); a3 = fmaf(w.w, rk, a3);
  }
  float ig = a0 + sh2g[lane];
  float fg = a1 + sh2g[64 + lane];
  float gg = a2 + sh2g[128 + lane];
  float og = a3 + sh2g[192 + lane];
  float c2 = sigf(fg) * c1g[lane] + sigf(ig) * tanhf(gg);
  float q2 = sigf(og) * tanhf(c2);
  qstarb[(size_t)wg * 128 + lane] = (unsigned short)f2bf(q2);

  // ---- attention step 2 (registers; online softmax) ----
  float r2v = 0.f;
  if (cnt > 0) {
    float q2v2 = q2 * LOG2E;
    float m0 = -INFINITY, l0 = 0.f, r0 = 0.f;
    float m1 = -INFINITY, l1 = 0.f, r1a = 0.f;
    if (fits) {
#pragma unroll
      for (int np = 0; np < CAPR / 2; np++) {
        int n = 2 * np;
        if (n < cnt) {
          bool hasB = (n + 1 < cnt);
          unsigned int p2 = pk[np];
          float nvA = bf2f(p2 & 0xffffu), nvB = bf2f(p2 >> 16);
          float e0 = wave_red(nvA * q2v2);
          float e1 = hasB ? wave_red(nvB * q2v2) : 0.f;
          if (e0 > m0 + THR) { float sc = fexp2(m0 - e0); l0 *= sc; r0 *= sc; m0 = e0; }
          float pA = fexp2(e0 - m0); l0 += pA; r0 = fmaf(pA, nvA, r0);
          if (hasB) {
            if (e1 > m1 + THR) { float sc = fexp2(m1 - e1); l1 *= sc; r1a *= sc; m1 = e1; }
            float pB = fexp2(e1 - m1); l1 += pB; r1a = fmaf(pB, nvB, r1a);
          }
        }
      }
    } else {
      const unsigned short* np_ = noisyFB + (size_t)n0 * 64 + lane;
      for (int n = 0; n < cnt; n++) {
        float nvA = bf2f(np_[(size_t)n * 64]);
        float e0 = wave_red(nvA * q2v2);
        if (e0 > m0 + THR) { float sc = fexp2(m0 - e0); l0 *= sc; r0 *= sc; m0 = e0; }
        float pA = fexp2(e0 - m0); l0 += pA; r0 = fmaf(pA, nvA, r0);
      }
    }
    float M = fmaxf(m0, m1);
    float sc0 = fexp2(m0 - M), sc1 = (m1 == -INFINITY) ? 0.f : fexp2(m1 - M);
    float L = l0 * sc0 + l1 * sc1;
    float R = r0 * sc0 + r1a * sc1;
    r2v = R / L;
  }
  qstarb[(size_t)wg * 128 + 64 + lane] = (unsigned short)f2bf(r2v);
}

// ---------------- K7/8/9: MFMA predictor layers (bf16 in, f32 accum) ----------------
// Wave = 16 rows x all col-tiles. A: row = lane&15, k = kt*32 + (lane>>4)*8 + j.
// C/D: col = lane&15, row = (lane>>4)*4 + j.
template <int KDIM, int ODIM, bool RELU, bool OUTF32>
__global__ __launch_bounds__(256) void k_linmfma(const unsigned short* __restrict__ A,
                                                 const unsigned short* __restrict__ WF,
                                                 const float* __restrict__ bias, void* __restrict__ Cv) {
  constexpr int NKF = KDIM / 32;
  constexpr int NCT = ODIM / 16;
  int tid = threadIdx.x, w = tid >> 6, l = tid & 63;
  int r0 = blockIdx.x * 64 + w * 16;
  int arow = r0 + (l & 15);
  int kb = (l >> 4) * 8;
  bf16x8 Af[NKF];
#pragma unroll
  for (int kf = 0; kf < NKF; kf++)
    Af[kf] = *(const bf16x8*)&A[(size_t)arow * KDIM + kf * 32 + kb];
  const bf16x8* wf = (const bf16x8*)WF;
  int c16 = l & 15, rg = l >> 4;
#pragma unroll
  for (int ct = 0; ct < NCT; ct++) {
    f32x4 acc = {0.f, 0.f, 0.f, 0.f};
#pragma unroll
    for (int kf = 0; kf < NKF; kf++)
      acc = __builtin_amdgcn_mfma_f32_16x16x32_bf16(Af[kf], wf[(ct * NKF + kf) * 64 + l], acc, 0, 0, 0);
    int col = ct * 16 + c16;
    float bb = bias[col];
#pragma unroll
    for (int j = 0; j < 4; j++) {
      float v = acc[j] + bb;
      if (RELU) v = fmaxf(v, 0.f);
      int row = r0 + rg * 4 + j;
      if (OUTF32) ((float*)Cv)[(size_t)row * ODIM + col] = v;
      else ((unsigned short*)Cv)[(size_t)row * ODIM + col] = (unsigned short)f2bf(v);
    }
  }
}

// ---------------- K10: final scalars ----------------
__global__ __launch_bounds__(256) void k_final(const float* __restrict__ klp, const int* __restrict__ presPart,
                                               float* __restrict__ out) {
  __shared__ float red[256];
  __shared__ int redi[256];
  float s = 0.0f;
  int pc = 0;
  for (int i = threadIdx.x; i < B_GR; i += 256) s += klp[i];
  for (int i = threadIdx.x; i < 8192; i += 256) pc += presPart[i];
  red[threadIdx.x] = s;
  redi[threadIdx.x] = pc;
  __syncthreads();
  for (int st = 128; st > 0; st >>= 1) {
    if (threadIdx.x < st) {
      red[threadIdx.x] += red[threadIdx.x + st];
      redi[threadIdx.x] += redi[threadIdx.x + st];
    }
    __syncthreads();
  }
  if (threadIdx.x == 0) {
    out[(size_t)B_GR * 64] = red[0] / (float)(B_GR * 64);
    out[(size_t)B_GR * 64 + 1] = (float)redi[0] / (float)N_TOT;
  }
}

// ---------------- launcher ----------------
extern "C" void kernel_launch(void* const* d_in, const int* in_sizes, int n_in,
                              void* d_out, int out_size, void* d_ws, size_t ws_size,
                              hipStream_t stream) {
  const float* features = (const float*)d_in[0];
  const int*   bidx     = (const int*)d_in[1];
  const float* eps_gate = (const float*)d_in[2];
  const float* noise    = (const float*)d_in[3];
  const float* c_w1 = (const float*)d_in[4];
  const float* c_b1 = (const float*)d_in[5];
  const float* bn_g = (const float*)d_in[6];
  const float* bn_b = (const float*)d_in[7];
  const float* c_w2 = (const float*)d_in[8];
  const float* c_b2 = (const float*)d_in[9];
  const float* wih  = (const float*)d_in[10];
  const float* whh  = (const float*)d_in[11];
  const float* bih  = (const float*)d_in[12];
  const float* bhh  = (const float*)d_in[13];
  const float* p_w1 = (const float*)d_in[14];
  const float* p_b1 = (const float*)d_in[15];
  const float* p_w2 = (const float*)d_in[16];
  const float* p_b2 = (const float*)d_in[17];
  const float* p_w3 = (const float*)d_in[18];
  const float* p_b3 = (const float*)d_in[19];
  float* out = (float*)d_out;

  float* wsf   = (float*)d_ws;
  int*   offp  = (int*)wsf;                                 // (B+1) ints
  float* pSum  = wsf + 16448;                               // 8192*64
  float* pSq   = pSum + 524288;                             // 8192*64
  float* aff   = pSq + 524288;                              // 128
  float* q1w   = aff + 128;                                 // 64
  float* c1w   = q1w + 64;                                  // 64
  float* sh2w  = c1w + 64;                                  // 256
  float* lamw  = sh2w + 256;                                // N
  float* rtgw  = lamw + (size_t)N_TOT;                      // 64*256 (RTg)
  unsigned short* wfragb = (unsigned short*)(rtgw + 16384); // 4096 ushorts (w1 frags)
  unsigned short* wf1 = wfragb + 4096;                      // 32768 ushorts (p_w1 frags)
  unsigned short* wf2 = wf1 + 32768;                        // 32768 ushorts (p_w2 frags)
  unsigned short* wf3 = wf2 + 32768;                        // 8192 ushorts (p_w3 frags)
  float* hwf = (float*)(wf3 + 8192);                        // N*64 float-sized region
  unsigned short* hb = (unsigned short*)hwf;                // h bf16; reused as noisy fallback
  unsigned short* noisyFB = hb;
  unsigned short* qstarb = (unsigned short*)(hwf + (size_t)N_TOT * 64);  // B*128 bf16
  unsigned short* z1b = qstarb + (size_t)B_GR * 128;        // B*256 bf16
  unsigned short* z2b = z1b + (size_t)B_GR * 256;           // B*128 bf16
  float* klpw = (float*)(z2b + (size_t)B_GR * 128);         // B floats
  int* presPart = (int*)(klpw + B_GR);                      // 8192 ints

  float* lamOut = out + (size_t)B_GR * 64 + 2;

  k_offsets<<<(B_GR + 1 + 255) / 256, 256, 0, stream>>>(bidx, offp);
  k_prep<<<64, 256, 0, stream>>>(c_w1, p_w1, p_w2, p_w3, wih, rtgw, wfragb, wf1, wf2, wf3);
  k_bn_stats<<<N_TOT / 64, 256, 0, stream>>>(features, wfragb, c_b1, hb, pSum, pSq);
  k_bn_final<<<64, 256, 0, stream>>>(pSum, pSq, bn_g, bn_b, aff);
  k_lstm1<<<1, 256, 0, stream>>>(bih, bhh, wih, whh, q1w, c1w, sh2w);
  k_gate_h<<<N_TOT / 64, 256, 0, stream>>>(hb, aff, c_w2, c_b2, eps_gate, lamw, lamOut, presPart);
  k_graph_reg<<<B_GR / 4, 256, 0, stream>>>(features, noise, lamw, offp, q1w, c1w, sh2w, rtgw,
                                            noisyFB, qstarb, klpw);
  k_linmfma<128, 256, true, false><<<B_GR / 64, 256, 0, stream>>>(qstarb, wf1, p_b1, z1b);
  k_linmfma<256, 128, true, false><<<B_GR / 64, 256, 0, stream>>>(z1b, wf2, p_b2, z2b);
  k_linmfma<128, 64, false, true><<<B_GR / 64, 256, 0, stream>>>(z2b, wf3, p_b3, out);
  k_final<<<1, 256, 0, stream>>>(klpw, presPart, out);
}

// Round 16
// 260.611 us; speedup vs baseline: 1.4119x; 1.0008x over previous
//
#include <hip/hip_runtime.h>
#include <math.h>

#define N_TOT 524288
#define B_GR  16384
#define CAPR  64

#define LOG2E 1.44269504088896f
#define LN2   0.69314718055995f

typedef __attribute__((ext_vector_type(8))) short bf16x8;
typedef __attribute__((ext_vector_type(4))) float f32x4;

// ---------------- small device helpers ----------------
__device__ __forceinline__ float fexp2(float x) { return __builtin_amdgcn_exp2f(x); }
__device__ __forceinline__ float flog2(float x) { return __builtin_amdgcn_logf(x); }
__device__ __forceinline__ float frcp(float x)  { return __builtin_amdgcn_rcpf(x); }
__device__ __forceinline__ float sigf(float x)  { return frcp(1.0f + fexp2(-x * LOG2E)); }

// bf16 pack/unpack (RNE)
__device__ __forceinline__ unsigned int f2bf(float x) {
  unsigned int u = __float_as_uint(x);
  return (u + 0x7FFFu + ((u >> 16) & 1u)) >> 16;
}
__device__ __forceinline__ float bf2f(unsigned int s) {
  return __uint_as_float(s << 16);
}

// ---- DPP-based 64-lane sum ----
template <int CTRL>
__device__ __forceinline__ float dppadd(float v) {
  return v + __int_as_float(__builtin_amdgcn_update_dpp(
      0, __float_as_int(v), CTRL, 0xF, 0xF, true));
}
__device__ __forceinline__ float wave_red(float v) {
  v = dppadd<0x111>(v);   // row_shr:1
  v = dppadd<0x112>(v);   // row_shr:2
  v = dppadd<0x114>(v);   // row_shr:4
  v = dppadd<0x118>(v);   // row_shr:8
  v = dppadd<0x142>(v);   // row_bcast15
  v = dppadd<0x143>(v);   // row_bcast31
  return __int_as_float(__builtin_amdgcn_readlane(__float_as_int(v), 63));
}

// ---- paired 64-lane sum: 12 ops for TWO reductions (vs 2x13).
// Fold offset-32 per value (2 shfl), pack a->lanes0-31 / b->lanes32-63 (cndmask),
// one DPP chain shr1/2/4/8 + bcast15: lane31 = full a-sum, lane63 = full b-sum.
__device__ __forceinline__ void wave_red2(float a, float b, bool lo, float& e0, float& e1) {
  float a2 = a + __shfl_xor(a, 32);
  float b2 = b + __shfl_xor(b, 32);
  float c = lo ? a2 : b2;
  c = dppadd<0x111>(c);
  c = dppadd<0x112>(c);
  c = dppadd<0x114>(c);
  c = dppadd<0x118>(c);   // lane 15/31/47/63 hold 16-row sums
  c = dppadd<0x142>(c);   // row_bcast15: lane31 = lanes0-31 sum, lane63 = lanes32-63 sum
  e0 = __int_as_float(__builtin_amdgcn_readlane(__float_as_int(c), 31));
  e1 = __int_as_float(__builtin_amdgcn_readlane(__float_as_int(c), 63));
}

// ---------------- K0a: graph offsets ----------------
__global__ void k_offsets(const int* __restrict__ idx, int* __restrict__ off) {
  int b = blockIdx.x * blockDim.x + threadIdx.x;
  if (b > B_GR) return;
  if (b == B_GR) { off[B_GR] = N_TOT; return; }
  int lo = 0, hi = N_TOT;
  while (lo < hi) { int mid = (lo + hi) >> 1; if (idx[mid] < b) lo = mid + 1; else hi = mid; }
  off[b] = lo;
}

// ---------------- K0b: RTg for fused LSTM2; bf16 MFMA B-fragments for all GEMMs ----------------
__global__ void k_prep(const float* __restrict__ w1, const float* __restrict__ pw1,
                       const float* __restrict__ pw2, const float* __restrict__ pw3,
                       const float* __restrict__ wih,
                       float* __restrict__ rtg, unsigned short* __restrict__ wfragb,
                       unsigned short* __restrict__ wf1, unsigned short* __restrict__ wf2,
                       unsigned short* __restrict__ wf3) {
  int t = blockIdx.x * 256 + threadIdx.x;
  for (int i = t; i < 64 * 64 * 4; i += 16384) {
    int k = i >> 8, rem = i & 255, d = rem >> 2, j = rem & 3;
    rtg[i] = wih[(size_t)(j * 64 + d) * 128 + 64 + k];
  }
  // w1 (K=64, O=64): NKF=2, NCT=4
  for (int i = t; i < 8 * 64 * 8; i += 16384) {
    int f = i >> 9, lane = (i >> 3) & 63, j = i & 7;
    int ct = f >> 1, kt = f & 1;
    int k = kt * 32 + (lane >> 4) * 8 + j;
    int col = ct * 16 + (lane & 15);
    wfragb[i] = (unsigned short)f2bf(w1[(size_t)col * 64 + k]);
  }
  // p_w1 (K=128, O=256): NKF=4, NCT=16
  for (int i = t; i < 64 * 64 * 8; i += 16384) {
    int f = i >> 9, lane = (i >> 3) & 63, j = i & 7;
    int ct = f >> 2, kt = f & 3;
    int k = kt * 32 + (lane >> 4) * 8 + j;
    int col = ct * 16 + (lane & 15);
    wf1[i] = (unsigned short)f2bf(pw1[(size_t)col * 128 + k]);
  }
  // p_w2 (K=256, O=128): NKF=8, NCT=8
  for (int i = t; i < 64 * 64 * 8; i += 16384) {
    int f = i >> 9, lane = (i >> 3) & 63, j = i & 7;
    int ct = f >> 3, kt = f & 7;
    int k = kt * 32 + (lane >> 4) * 8 + j;
    int col = ct * 16 + (lane & 15);
    wf2[i] = (unsigned short)f2bf(pw2[(size_t)col * 256 + k]);
  }
  // p_w3 (K=128, O=64): NKF=4, NCT=4
  for (int i = t; i < 16 * 64 * 8; i += 16384) {
    int f = i >> 9, lane = (i >> 3) & 63, j = i & 7;
    int ct = f >> 2, kt = f & 3;
    int k = kt * 32 + (lane >> 4) * 8 + j;
    int col = ct * 16 + (lane & 15);
    wf3[i] = (unsigned short)f2bf(pw3[(size_t)col * 128 + k]);
  }
}

// ---------------- K1: MFMA h = X@W1^T + b1 -> bf16 h; stats partials ----------------
__global__ __launch_bounds__(256) void k_bn_stats(const float* __restrict__ X,
                                                  const unsigned short* __restrict__ wfragb,
                                                  const float* __restrict__ b1, unsigned short* __restrict__ h,
                                                  float* __restrict__ pSum, float* __restrict__ pSq) {
  __shared__ float redS[16][64];
  __shared__ float redQ[16][64];
  int tid = threadIdx.x, w = tid >> 6, l = tid & 63;
  int n0 = blockIdx.x * 64;
  int r0 = w * 16;
  int arow = n0 + r0 + (l & 15);
  int kb = (l >> 4) * 8;
  const float* xr = X + (size_t)arow * 64 + kb;
  float4 a00 = *(const float4*)&xr[0];
  float4 a01 = *(const float4*)&xr[4];
  float4 a10 = *(const float4*)&xr[32];
  float4 a11 = *(const float4*)&xr[36];
  bf16x8 A0, A1;
  A0[0] = (short)f2bf(a00.x); A0[1] = (short)f2bf(a00.y); A0[2] = (short)f2bf(a00.z); A0[3] = (short)f2bf(a00.w);
  A0[4] = (short)f2bf(a01.x); A0[5] = (short)f2bf(a01.y); A0[6] = (short)f2bf(a01.z); A0[7] = (short)f2bf(a01.w);
  A1[0] = (short)f2bf(a10.x); A1[1] = (short)f2bf(a10.y); A1[2] = (short)f2bf(a10.z); A1[3] = (short)f2bf(a10.w);
  A1[4] = (short)f2bf(a11.x); A1[5] = (short)f2bf(a11.y); A1[6] = (short)f2bf(a11.z); A1[7] = (short)f2bf(a11.w);
  const bf16x8* wf = (const bf16x8*)wfragb;
  f32x4 acc0 = {0.f, 0.f, 0.f, 0.f}, acc1 = acc0, acc2 = acc0, acc3 = acc0;
  {
    bf16x8 B00 = wf[0 * 64 + l], B01 = wf[1 * 64 + l];
    bf16x8 B10 = wf[2 * 64 + l], B11 = wf[3 * 64 + l];
    bf16x8 B20 = wf[4 * 64 + l], B21 = wf[5 * 64 + l];
    bf16x8 B30 = wf[6 * 64 + l], B31 = wf[7 * 64 + l];
    acc0 = __builtin_amdgcn_mfma_f32_16x16x32_bf16(A0, B00, acc0, 0, 0, 0);
    acc0 = __builtin_amdgcn_mfma_f32_16x16x32_bf16(A1, B01, acc0, 0, 0, 0);
    acc1 = __builtin_amdgcn_mfma_f32_16x16x32_bf16(A0, B10, acc1, 0, 0, 0);
    acc1 = __builtin_amdgcn_mfma_f32_16x16x32_bf16(A1, B11, acc1, 0, 0, 0);
    acc2 = __builtin_amdgcn_mfma_f32_16x16x32_bf16(A0, B20, acc2, 0, 0, 0);
    acc2 = __builtin_amdgcn_mfma_f32_16x16x32_bf16(A1, B21, acc2, 0, 0, 0);
    acc3 = __builtin_amdgcn_mfma_f32_16x16x32_bf16(A0, B30, acc3, 0, 0, 0);
    acc3 = __builtin_amdgcn_mfma_f32_16x16x32_bf16(A1, B31, acc3, 0, 0, 0);
  }
  int c16 = l & 15, rgrp = l >> 4;
  int slot = w * 4 + rgrp;
#pragma unroll
  for (int ct = 0; ct < 4; ct++) {
    f32x4 acc = (ct == 0) ? acc0 : (ct == 1) ? acc1 : (ct == 2) ? acc2 : acc3;
    int col = ct * 16 + c16;
    float bb = b1[col];
    float cs = 0.f, cq = 0.f;
#pragma unroll
    for (int j = 0; j < 4; j++) {
      float hv = acc[j] + bb;
      int row = n0 + r0 + rgrp * 4 + j;
      h[(size_t)row * 64 + col] = (unsigned short)f2bf(hv);
      cs += hv; cq = fmaf(hv, hv, cq);
    }
    redS[slot][col] = cs;
    redQ[slot][col] = cq;
  }
  __syncthreads();
  if (tid < 64) {
    float s = 0.f, q = 0.f;
#pragma unroll
    for (int t = 0; t < 16; t++) { s += redS[t][tid]; q += redQ[t][tid]; }
    pSum[(size_t)blockIdx.x * 64 + tid] = s;
    pSq[(size_t)blockIdx.x * 64 + tid] = q;
  }
}

// ---------------- K2a: finalize BN -> affine ----------------
__global__ __launch_bounds__(256) void k_bn_final(const float* __restrict__ pSum, const float* __restrict__ pSq,
                                                  const float* __restrict__ bn_g, const float* __restrict__ bn_b,
                                                  float* __restrict__ aff) {
  int c = blockIdx.x;
  float s = 0, q = 0;
  for (int i = threadIdx.x; i < 8192; i += 256) {
    s += pSum[(size_t)i * 64 + c];
    q += pSq[(size_t)i * 64 + c];
  }
  __shared__ float rs[256], rq[256];
  rs[threadIdx.x] = s; rq[threadIdx.x] = q;
  __syncthreads();
  for (int st = 128; st > 0; st >>= 1) {
    if (threadIdx.x < st) { rs[threadIdx.x] += rs[threadIdx.x + st]; rq[threadIdx.x] += rq[threadIdx.x + st]; }
    __syncthreads();
  }
  if (threadIdx.x == 0) {
    float mu = rs[0] / (float)N_TOT;
    float var = rq[0] / (float)N_TOT - mu * mu;
    var = fmaxf(var, 0.0f);
    float A = bn_g[c] * rsqrtf(var + 1e-5f);
    aff[c] = A;
    aff[64 + c] = bn_b[c] - mu * A;
  }
}

// ---------------- K2b: LSTM step1 ----------------
__global__ __launch_bounds__(256) void k_lstm1(const float* __restrict__ bih, const float* __restrict__ bhh,
                                               const float* __restrict__ wih, const float* __restrict__ whh,
                                               float* __restrict__ q1, float* __restrict__ c1, float* __restrict__ sh2) {
  __shared__ float g1[256];
  __shared__ float q1s[64];
  int tid = threadIdx.x;
  g1[tid] = bih[tid] + bhh[tid];
  __syncthreads();
  if (tid < 64) {
    float ig = sigf(g1[tid]);
    float gg = tanhf(g1[128 + tid]);
    float cc = ig * gg;
    float og = sigf(g1[192 + tid]);
    float qv = og * tanhf(cc);
    q1s[tid] = qv; q1[tid] = qv; c1[tid] = cc;
  }
  __syncthreads();
  float acc = g1[tid];
  for (int k = 0; k < 64; k++)
    acc = fmaf(wih[(size_t)tid * 128 + k] + whh[(size_t)tid * 64 + k], q1s[k], acc);
  sh2[tid] = acc;
}

// ---------------- K3: streaming gate (no atomics) ----------------
__global__ __launch_bounds__(256) void k_gate_h(const unsigned short* __restrict__ h, const float* __restrict__ aff,
                                                const float* __restrict__ w2, const float* __restrict__ cb2,
                                                const float* __restrict__ eps_gate,
                                                float* __restrict__ lamWS, float* __restrict__ lamOut,
                                                int* __restrict__ presPart) {
  __shared__ float Hs[64][65];
  __shared__ float A2s[64], C2s[64], w2s[64];
  __shared__ int pcnt[4];
  int tid = threadIdx.x;
  if (tid < 64) { A2s[tid] = aff[tid]; C2s[tid] = aff[64 + tid]; w2s[tid] = w2[tid]; }
  int n0 = blockIdx.x * 64;
#pragma unroll
  for (int s = 0; s < 4; s++) {
    int e4 = tid * 4 + s * 1024;
    int r = e4 >> 6, c = e4 & 63;
    ushort4 v = *(const ushort4*)&h[(size_t)(n0 + r) * 64 + c];
    Hs[r][c] = bf2f(v.x); Hs[r][c + 1] = bf2f(v.y);
    Hs[r][c + 2] = bf2f(v.z); Hs[r][c + 3] = bf2f(v.w);
  }
  __syncthreads();
  int r = tid >> 2, q = tid & 3;
  float p = 0.f;
#pragma unroll
  for (int j = 0; j < 16; j++) {
    int d = q * 16 + j;
    p = fmaf(fmaxf(fmaf(Hs[r][d], A2s[d], C2s[d]), 0.f), w2s[d], p);
  }
  p += __shfl_xor(p, 1);
  p += __shfl_xor(p, 2);
  p += cb2[0];
  unsigned long long m = __ballot(q == 0 && p > 0.0f);
  if ((tid & 63) == 0) pcnt[tid >> 6] = (int)__popcll(m);
  if (q == 0) {
    int row = n0 + r;
    float eg = eps_gate[row];
    float eps = 0.9999f - 0.9998f * eg;
    float gi = (flog2(eps) - flog2(1.0f - eps)) * LN2;
    float lam = sigf(gi + p);
    lamWS[row] = lam;
    lamOut[row] = lam;
  }
  __syncthreads();
  if (tid == 0) presPart[blockIdx.x] = pcnt[0] + pcnt[1] + pcnt[2] + pcnt[3];
}

// ---------------- K4: register-resident wave-per-graph, paired DPP reductions ----------------
__global__ __launch_bounds__(256) void k_graph_reg(const float* __restrict__ X, const float* __restrict__ noise,
                                                   const float* __restrict__ lam, const int* __restrict__ off,
                                                   const float* __restrict__ q1g, const float* __restrict__ c1g,
                                                   const float* __restrict__ sh2g, const float* __restrict__ rtg,
                                                   unsigned short* __restrict__ noisyFB, unsigned short* __restrict__ qstarb,
                                                   float* __restrict__ klp) {
  int wg = blockIdx.x * 4 + (threadIdx.x >> 6);
  int lane = threadIdx.x & 63;
  bool lo = lane < 32;
  int n0 = off[wg], cnt = off[wg + 1] - n0;
  const float THR = 8.f;
  const float* xp = X + (size_t)n0 * 64 + lane;
  const float* zp = noise + (size_t)n0 * 64 + lane;
  float r1v = 0.f;
  bool fits = (cnt <= CAPR);
  unsigned int pk[CAPR / 2];

  if (cnt > 0 && fits) {
    float s0 = 0.f, q0 = 0.f, s1 = 0.f, q1_ = 0.f;
#pragma unroll
    for (int np = 0; np < CAPR / 2; np++) {
      int n = 2 * np;
      if (n < cnt) {
        float a = xp[(size_t)n * 64];
        s0 += a; q0 = fmaf(a, a, q0);
        float b = 0.f;
        if (n + 1 < cnt) {
          b = xp[(size_t)(n + 1) * 64];
          s1 += b; q1_ = fmaf(b, b, q1_);
        }
        pk[np] = (f2bf(b) << 16) | f2bf(a);
      }
    }
    float c = (float)cnt;
    float mean = (s0 + s1) / c;
    float var = fmaxf(((q0 + q1_) - c * mean * mean) / fmaxf(c - 1.f, 1.f), 0.f);
    float sd = sqrtf(var);
    float inv = frcp(sd + 1e-7f);
    float S1 = wave_red(sd * sd * inv * inv);
    float q1v2 = q1g[lane] * LOG2E;
    float t2acc = 0.f, sumOm2 = 0.f;
    float m0 = -INFINITY, l0 = 0.f, r0 = 0.f;
    float m1 = -INFINITY, l1 = 0.f, r1a = 0.f;
#pragma unroll
    for (int np = 0; np < CAPR / 2; np++) {
      int n = 2 * np;
      if (n < cnt) {
        bool hasB = (n + 1 < cnt);
        unsigned int p2 = pk[np];
        float xA = bf2f(p2 & 0xffffu), xB = bf2f(p2 >> 16);
        float lamA = lam[n0 + n];
        float zA = zp[(size_t)n * 64];
        float lamB = hasB ? lam[n0 + n + 1] : 0.f;
        float zB = hasB ? zp[(size_t)(n + 1) * 64] : 0.f;
        float omA = 1.f - lamA, omB = 1.f - lamB;
        float nvA = fmaf(lamA, xA, omA * mean) + zA * (omA * sd);
        float nvB = fmaf(lamB, xB, omB * mean) + zB * (omB * sd);
        pk[np] = (f2bf(nvB) << 16) | f2bf(nvA);
        float ldA = lamA * (xA - mean) * inv; t2acc = fmaf(ldA, ldA, t2acc);
        sumOm2 = fmaf(omA, omA, sumOm2);
        if (hasB) {
          float ldB = lamB * (xB - mean) * inv; t2acc = fmaf(ldB, ldB, t2acc);
          sumOm2 = fmaf(omB, omB, sumOm2);
        }
        float e0, e1;
        wave_red2(nvA * q1v2, hasB ? nvB * q1v2 : 0.f, lo, e0, e1);
        if (e0 > m0 + THR) { float sc = fexp2(m0 - e0); l0 *= sc; r0 *= sc; m0 = e0; }
        float pA = fexp2(e0 - m0); l0 += pA; r0 = fmaf(pA, nvA, r0);
        if (hasB) {
          if (e1 > m1 + THR) { float sc = fexp2(m1 - e1); l1 *= sc; r1a *= sc; m1 = e1; }
          float pB = fexp2(e1 - m1); l1 += pB; r1a = fmaf(pB, nvB, r1a);
        }
      }
    }
    float M = fmaxf(m0, m1);
    float sc0 = fexp2(m0 - M), sc1 = (m1 == -INFINITY) ? 0.f : fexp2(m1 - M);
    float L = l0 * sc0 + l1 * sc1;
    float R = r0 * sc0 + r1a * sc1;
    r1v = R / L;
    float t2tot = wave_red(t2acc);
    if (lane == 0) klp[wg] = fmaf(0.5f * sumOm2, S1, t2tot);
  } else if (cnt > 0) {
    unsigned short* nw = noisyFB + (size_t)n0 * 64 + lane;
    float s0 = 0.f, q0 = 0.f;
    for (int n = 0; n < cnt; n++) { float a = xp[(size_t)n * 64]; s0 += a; q0 = fmaf(a, a, q0); }
    float c = (float)cnt;
    float mean = s0 / c;
    float var = fmaxf((q0 - c * mean * mean) / fmaxf(c - 1.f, 1.f), 0.f);
    float sd = sqrtf(var);
    float inv = frcp(sd + 1e-7f);
    float S1 = wave_red(sd * sd * inv * inv);
    float q1v2 = q1g[lane] * LOG2E;
    float t2acc = 0.f, sumOm2 = 0.f;
    float m0 = -INFINITY, l0 = 0.f, r0 = 0.f;
    for (int n = 0; n < cnt; n++) {
      float lamA = lam[n0 + n];
      float xA = xp[(size_t)n * 64];
      float zA = zp[(size_t)n * 64];
      float omA = 1.f - lamA;
      float nvA = fmaf(lamA, xA, omA * mean) + zA * (omA * sd);
      nw[(size_t)n * 64] = (unsigned short)f2bf(nvA);
      float ldA = lamA * (xA - mean) * inv; t2acc = fmaf(ldA, ldA, t2acc);
      sumOm2 = fmaf(omA, omA, sumOm2);
      float e0 = wave_red(nvA * q1v2);
      if (e0 > m0 + THR) { float sc = fexp2(m0 - e0); l0 *= sc; r0 *= sc; m0 = e0; }
      float pA = fexp2(e0 - m0); l0 += pA; r0 = fmaf(pA, nvA, r0);
    }
    r1v = r0 / l0;
    float t2tot = wave_red(t2acc);
    if (lane == 0) klp[wg] = fmaf(0.5f * sumOm2, S1, t2tot);
  } else {
    if (lane == 0) klp[wg] = 0.0f;
  }

  // ---- fused LSTM step 2 ----
  float a0 = 0.f, a1 = 0.f, a2 = 0.f, a3 = 0.f;
  const float4* rt = (const float4*)rtg;
#pragma unroll 4
  for (int k = 0; k < 64; k++) {
    float rk = __shfl(r1v, k);
    float4 w = rt[k * 64 + lane];
    a0 = fmaf(w.x, rk, a0); a1 = fmaf(w.y, rk, a1);
    a2 = fmaf(w.z, rk, a2); a3 = fmaf(w.w, rk, a3);
  }
  float ig = a0 + sh2g[lane];
  float fg = a1 + sh2g[64 + lane];
  float gg = a2 + sh2g[128 + lane];
  float og = a3 + sh2g[192 + lane];
  float c2 = sigf(fg) * c1g[lane] + sigf(ig) * tanhf(gg);
  float q2 = sigf(og) * tanhf(c2);
  qstarb[(size_t)wg * 128 + lane] = (unsigned short)f2bf(q2);

  // ---- attention step 2 (registers; online softmax, paired reductions) ----
  float r2v = 0.f;
  if (cnt > 0) {
    float q2v2 = q2 * LOG2E;
    float m0 = -INFINITY, l0 = 0.f, r0 = 0.f;
    float m1 = -INFINITY, l1 = 0.f, r1a = 0.f;
    if (fits) {
#pragma unroll
      for (int np = 0; np < CAPR / 2; np++) {
        int n = 2 * np;
        if (n < cnt) {
          bool hasB = (n + 1 < cnt);
          unsigned int p2 = pk[np];
          float nvA = bf2f(p2 & 0xffffu), nvB = bf2f(p2 >> 16);
          float e0, e1;
          wave_red2(nvA * q2v2, hasB ? nvB * q2v2 : 0.f, lo, e0, e1);
          if (e0 > m0 + THR) { float sc = fexp2(m0 - e0); l0 *= sc; r0 *= sc; m0 = e0; }
          float pA = fexp2(e0 - m0); l0 += pA; r0 = fmaf(pA, nvA, r0);
          if (hasB) {
            if (e1 > m1 + THR) { float sc = fexp2(m1 - e1); l1 *= sc; r1a *= sc; m1 = e1; }
            float pB = fexp2(e1 - m1); l1 += pB; r1a = fmaf(pB, nvB, r1a);
          }
        }
      }
    } else {
      const unsigned short* np_ = noisyFB + (size_t)n0 * 64 + lane;
      for (int n = 0; n < cnt; n++) {
        float nvA = bf2f(np_[(size_t)n * 64]);
        float e0 = wave_red(nvA * q2v2);
        if (e0 > m0 + THR) { float sc = fexp2(m0 - e0); l0 *= sc; r0 *= sc; m0 = e0; }
        float pA = fexp2(e0 - m0); l0 += pA; r0 = fmaf(pA, nvA, r0);
      }
    }
    float M = fmaxf(m0, m1);
    float sc0 = fexp2(m0 - M), sc1 = (m1 == -INFINITY) ? 0.f : fexp2(m1 - M);
    float L = l0 * sc0 + l1 * sc1;
    float R = r0 * sc0 + r1a * sc1;
    r2v = R / L;
  }
  qstarb[(size_t)wg * 128 + 64 + lane] = (unsigned short)f2bf(r2v);
}

// ---------------- K7/8/9: MFMA predictor layers (bf16 in, f32 accum) ----------------
template <int KDIM, int ODIM, bool RELU, bool OUTF32>
__global__ __launch_bounds__(256) void k_linmfma(const unsigned short* __restrict__ A,
                                                 const unsigned short* __restrict__ WF,
                                                 const float* __restrict__ bias, void* __restrict__ Cv) {
  constexpr int NKF = KDIM / 32;
  constexpr int NCT = ODIM / 16;
  int tid = threadIdx.x, w = tid >> 6, l = tid & 63;
  int r0 = blockIdx.x * 64 + w * 16;
  int arow = r0 + (l & 15);
  int kb = (l >> 4) * 8;
  bf16x8 Af[NKF];
#pragma unroll
  for (int kf = 0; kf < NKF; kf++)
    Af[kf] = *(const bf16x8*)&A[(size_t)arow * KDIM + kf * 32 + kb];
  const bf16x8* wf = (const bf16x8*)WF;
  int c16 = l & 15, rg = l >> 4;
#pragma unroll
  for (int ct = 0; ct < NCT; ct++) {
    f32x4 acc = {0.f, 0.f, 0.f, 0.f};
#pragma unroll
    for (int kf = 0; kf < NKF; kf++)
      acc = __builtin_amdgcn_mfma_f32_16x16x32_bf16(Af[kf], wf[(ct * NKF + kf) * 64 + l], acc, 0, 0, 0);
    int col = ct * 16 + c16;
    float bb = bias[col];
#pragma unroll
    for (int j = 0; j < 4; j++) {
      float v = acc[j] + bb;
      if (RELU) v = fmaxf(v, 0.f);
      int row = r0 + rg * 4 + j;
      if (OUTF32) ((float*)Cv)[(size_t)row * ODIM + col] = v;
      else ((unsigned short*)Cv)[(size_t)row * ODIM + col] = (unsigned short)f2bf(v);
    }
  }
}

// ---------------- K10: final scalars ----------------
__global__ __launch_bounds__(256) void k_final(const float* __restrict__ klp, const int* __restrict__ presPart,
                                               float* __restrict__ out) {
  __shared__ float red[256];
  __shared__ int redi[256];
  float s = 0.0f;
  int pc = 0;
  for (int i = threadIdx.x; i < B_GR; i += 256) s += klp[i];
  for (int i = threadIdx.x; i < 8192; i += 256) pc += presPart[i];
  red[threadIdx.x] = s;
  redi[threadIdx.x] = pc;
  __syncthreads();
  for (int st = 128; st > 0; st >>= 1) {
    if (threadIdx.x < st) {
      red[threadIdx.x] += red[threadIdx.x + st];
      redi[threadIdx.x] += redi[threadIdx.x + st];
    }
    __syncthreads();
  }
  if (threadIdx.x == 0) {
    out[(size_t)B_GR * 64] = red[0] / (float)(B_GR * 64);
    out[(size_t)B_GR * 64 + 1] = (float)redi[0] / (float)N_TOT;
  }
}

// ---------------- launcher ----------------
extern "C" void kernel_launch(void* const* d_in, const int* in_sizes, int n_in,
                              void* d_out, int out_size, void* d_ws, size_t ws_size,
                              hipStream_t stream) {
  const float* features = (const float*)d_in[0];
  const int*   bidx     = (const int*)d_in[1];
  const float* eps_gate = (const float*)d_in[2];
  const float* noise    = (const float*)d_in[3];
  const float* c_w1 = (const float*)d_in[4];
  const float* c_b1 = (const float*)d_in[5];
  const float* bn_g = (const float*)d_in[6];
  const float* bn_b = (const float*)d_in[7];
  const float* c_w2 = (const float*)d_in[8];
  const float* c_b2 = (const float*)d_in[9];
  const float* wih  = (const float*)d_in[10];
  const float* whh  = (const float*)d_in[11];
  const float* bih  = (const float*)d_in[12];
  const float* bhh  = (const float*)d_in[13];
  const float* p_w1 = (const float*)d_in[14];
  const float* p_b1 = (const float*)d_in[15];
  const float* p_w2 = (const float*)d_in[16];
  const float* p_b2 = (const float*)d_in[17];
  const float* p_w3 = (const float*)d_in[18];
  const float* p_b3 = (const float*)d_in[19];
  float* out = (float*)d_out;

  float* wsf   = (float*)d_ws;
  int*   offp  = (int*)wsf;                                 // (B+1) ints
  float* pSum  = wsf + 16448;                               // 8192*64
  float* pSq   = pSum + 524288;                             // 8192*64
  float* aff   = pSq + 524288;                              // 128
  float* q1w   = aff + 128;                                 // 64
  float* c1w   = q1w + 64;                                  // 64
  float* sh2w  = c1w + 64;                                  // 256
  float* lamw  = sh2w + 256;                                // N
  float* rtgw  = lamw + (size_t)N_TOT;                      // 64*256 (RTg)
  unsigned short* wfragb = (unsigned short*)(rtgw + 16384); // 4096 ushorts (w1 frags)
  unsigned short* wf1 = wfragb + 4096;                      // 32768 ushorts (p_w1 frags)
  unsigned short* wf2 = wf1 + 32768;                        // 32768 ushorts (p_w2 frags)
  unsigned short* wf3 = wf2 + 32768;                        // 8192 ushorts (p_w3 frags)
  float* hwf = (float*)(wf3 + 8192);                        // N*64 float-sized region
  unsigned short* hb = (unsigned short*)hwf;                // h bf16; reused as noisy fallback
  unsigned short* noisyFB = hb;
  unsigned short* qstarb = (unsigned short*)(hwf + (size_t)N_TOT * 64);  // B*128 bf16
  unsigned short* z1b = qstarb + (size_t)B_GR * 128;        // B*256 bf16
  unsigned short* z2b = z1b + (size_t)B_GR * 256;           // B*128 bf16
  float* klpw = (float*)(z2b + (size_t)B_GR * 128);         // B floats
  int* presPart = (int*)(klpw + B_GR);                      // 8192 ints

  float* lamOut = out + (size_t)B_GR * 64 + 2;

  k_offsets<<<(B_GR + 1 + 255) / 256, 256, 0, stream>>>(bidx, offp);
  k_prep<<<64, 256, 0, stream>>>(c_w1, p_w1, p_w2, p_w3, wih, rtgw, wfragb, wf1, wf2, wf3);
  k_bn_stats<<<N_TOT / 64, 256, 0, stream>>>(features, wfragb, c_b1, hb, pSum, pSq);
  k_bn_final<<<64, 256, 0, stream>>>(pSum, pSq, bn_g, bn_b, aff);
  k_lstm1<<<1, 256, 0, stream>>>(bih, bhh, wih, whh, q1w, c1w, sh2w);
  k_gate_h<<<N_TOT / 64, 256, 0, stream>>>(hb, aff, c_w2, c_b2, eps_gate, lamw, lamOut, presPart);
  k_graph_reg<<<B_GR / 4, 256, 0, stream>>>(features, noise, lamw, offp, q1w, c1w, sh2w, rtgw,
                                            noisyFB, qstarb, klpw);
  k_linmfma<128, 256, true, false><<<B_GR / 64, 256, 0, stream>>>(qstarb, wf1, p_b1, z1b);
  k_linmfma<256, 128, true, false><<<B_GR / 64, 256, 0, stream>>>(z1b, wf2, p_b2, z2b);
  k_linmfma<128, 64, false, true><<<B_GR / 64, 256, 0, stream>>>(z2b, wf3, p_b3, out);
  k_final<<<1, 256, 0, stream>>>(klpw, presPart, out);
}